// Round 1
// 1296.075 us; speedup vs baseline: 1.0045x; 1.0045x over previous
//
#include <hip/hip_runtime.h>

// out[b,g] = sum_l x[b,g,l] * W[l,g] + bias[g]
// x: (8192, 8, 4096) fp32, W: (1, 4096, 8) fp32, bias: (8,) fp32 -> out (8192, 8) fp32
// Memory-bound: 1.074 GB of x read once. Roofline ~170 us at 6.3 TB/s achievable.
//
// Structure: persistent-ish waves. Each wave owns ONE group g (rows with stride G
// share g), loads its per-lane weight slice (16 x float4 = 64 VGPR) into registers
// ONCE, then streams 16 rows of x, 2 rows per iteration (32 independent float4
// loads = 32 KB in flight per wave) so the HBM pipe never drains.

constexpr int Bsz = 8192;
constexpr int G   = 8;
constexpr int L   = 4096;
constexpr int L4  = L / 4;      // 1024 float4 per row
constexpr int NF  = L4 / 64;    // 16 float4 per lane per row

constexpr int NBLOCKS       = 1024;                // 256 threads = 4 waves each
constexpr int WAVES_TOTAL   = NBLOCKS * 4;         // 4096
constexpr int WAVES_PER_G   = WAVES_TOTAL / G;     // 512
constexpr int ROWS_PER_WAVE = Bsz / WAVES_PER_G;   // 16 (exact, no tail)

// Transpose weight (L,G) -> (G,L) so the main kernel loads it with coalesced float4.
__global__ __launch_bounds__(256) void transpose_w_kernel(const float* __restrict__ w,
                                                          float* __restrict__ wt) {
    int idx = blockIdx.x * 256 + threadIdx.x;   // over L*G = 32768
    if (idx < L * G) {
        int l = idx >> 3;       // idx / G
        int g = idx & (G - 1);  // idx % G
        wt[g * L + l] = w[idx];
    }
}

template <bool TRANSPOSED>
__global__ __launch_bounds__(256, 2) void gfc_kernel(const float* __restrict__ x,
                                                     const float* __restrict__ w,
                                                     const float* __restrict__ bias,
                                                     float* __restrict__ out) {
    const int wid  = threadIdx.x >> 6;            // wave in block: 0..3
    const int lane = threadIdx.x & 63;
    const int wave = blockIdx.x * 4 + wid;        // 0 .. WAVES_TOTAL-1
    const int g    = wave & (G - 1);              // constant group per wave
    const int wg   = wave >> 3;                   // 0 .. WAVES_PER_G-1

    // ---- weights: load once into registers (64 VGPR), reuse for all 16 rows ----
    float4 wv[NF];
    if (TRANSPOSED) {
        const float4* __restrict__ wr =
            reinterpret_cast<const float4*>(w) + (size_t)g * L4 + lane;
#pragma unroll
        for (int it = 0; it < NF; ++it) wv[it] = wr[it * 64];
    } else {
        // one-time strided gather straight from L2 (weight is 128 KiB, cache-hot)
#pragma unroll
        for (int it = 0; it < NF; ++it) {
            int l = (it * 64 + lane) * 4;
            wv[it].x = w[(l + 0) * G + g];
            wv[it].y = w[(l + 1) * G + g];
            wv[it].z = w[(l + 2) * G + g];
            wv[it].w = w[(l + 3) * G + g];
        }
    }

    const float bg = bias[g];
    const float4* __restrict__ xbase = reinterpret_cast<const float4*>(x);
    const int b0 = wg * ROWS_PER_WAVE;

#pragma unroll 1
    for (int k = 0; k < ROWS_PER_WAVE; k += 2) {
        const int rowA = (b0 + k)     * G + g;
        const int rowB = (b0 + k + 1) * G + g;
        const float4* __restrict__ xa = xbase + (size_t)rowA * L4 + lane;
        const float4* __restrict__ xb = xbase + (size_t)rowB * L4 + lane;

        // issue all 32 loads (2 rows x 16 float4) before any use: 32 KB in flight
        float4 va[NF], vb[NF];
#pragma unroll
        for (int it = 0; it < NF; ++it) va[it] = xa[it * 64];
#pragma unroll
        for (int it = 0; it < NF; ++it) vb[it] = xb[it * 64];

        float accA[4] = {0.f, 0.f, 0.f, 0.f};
        float accB[4] = {0.f, 0.f, 0.f, 0.f};
#pragma unroll
        for (int it = 0; it < NF; ++it) {
            float4 xv = va[it], wq = wv[it];
            float t = accA[it & 3];
            t = fmaf(xv.x, wq.x, t);
            t = fmaf(xv.y, wq.y, t);
            t = fmaf(xv.z, wq.z, t);
            t = fmaf(xv.w, wq.w, t);
            accA[it & 3] = t;
        }
#pragma unroll
        for (int it = 0; it < NF; ++it) {
            float4 xv = vb[it], wq = wv[it];
            float t = accB[it & 3];
            t = fmaf(xv.x, wq.x, t);
            t = fmaf(xv.y, wq.y, t);
            t = fmaf(xv.z, wq.z, t);
            t = fmaf(xv.w, wq.w, t);
            accB[it & 3] = t;
        }

        float sA = (accA[0] + accA[1]) + (accA[2] + accA[3]);
        float sB = (accB[0] + accB[1]) + (accB[2] + accB[3]);

        // 64-lane wave reduction, both rows in parallel (independent shuffle chains)
#pragma unroll
        for (int off = 32; off > 0; off >>= 1) {
            sA += __shfl_down(sA, off, 64);
            sB += __shfl_down(sB, off, 64);
        }

        if (lane == 0) {
            out[rowA] = sA + bg;
            out[rowB] = sB + bg;
        }
    }
}

extern "C" void kernel_launch(void* const* d_in, const int* in_sizes, int n_in,
                              void* d_out, int out_size, void* d_ws, size_t ws_size,
                              hipStream_t stream) {
    const float* x    = (const float*)d_in[0];
    const float* w    = (const float*)d_in[1];
    const float* bias = (const float*)d_in[2];
    float* out        = (float*)d_out;

    if (ws_size >= (size_t)(L * G) * sizeof(float)) {
        float* wt = (float*)d_ws;
        transpose_w_kernel<<<(L * G + 255) / 256, 256, 0, stream>>>(w, wt);
        gfc_kernel<true><<<NBLOCKS, 256, 0, stream>>>(x, wt, bias, out);
    } else {
        gfc_kernel<false><<<NBLOCKS, 256, 0, stream>>>(x, w, bias, out);
    }
}